// Round 1
// baseline (4053.244 us; speedup 1.0000x reference)
//
#include <hip/hip_runtime.h>

#define B_    32
#define CIN_  96
#define EXC_  102
#define INH_  26
#define HH    64
#define WW    64
#define HW_   4096
#define NPOS  (B_*HW_)   // 131072

__device__ __forceinline__ int refl(int i) {
    if (i < 0) i = -i;
    if (i > 63) i = 126 - i;
    return i;
}

// Direct 5x5 conv with reflect padding. Block = 16x16 output tile, TE output
// channels per thread. Optional ReLU and optional elementwise add (residual).
// addin may alias out (read happens at the same element before write).
template<int CIN, int TE>
__global__ __launch_bounds__(256) void conv5x5_kernel(
    const float* __restrict__ in, const float* __restrict__ w,
    const float* __restrict__ addin, float* __restrict__ out,
    int Cout, int do_relu)
{
    __shared__ float sx[20*20];
    __shared__ float sw[TE*25];
    const int tx = threadIdx.x, ty = threadIdx.y;
    const int tid = ty*16 + tx;
    const int tile = blockIdx.x;            // 0..15 (4x4 tiles of 16x16)
    const int e0 = blockIdx.y * TE;
    const int b  = blockIdx.z;
    const int h0 = (tile >> 2) * 16;
    const int w0 = (tile &  3) * 16;

    float acc[TE];
#pragma unroll
    for (int e = 0; e < TE; ++e) acc[e] = 0.f;

    for (int c = 0; c < CIN; ++c) {
        const float* inc = in + ((size_t)(b*CIN + c)) * HW_;
        for (int i = tid; i < 400; i += 256) {
            int lh = i / 20, lw = i - lh*20;
            int gh = refl(h0 - 2 + lh), gw = refl(w0 - 2 + lw);
            sx[i] = inc[gh*WW + gw];
        }
        for (int i = tid; i < TE*25; i += 256) {
            int e = i / 25, k = i - e*25;
            sw[i] = w[((size_t)(e0 + e)*CIN + c)*25 + k];
        }
        __syncthreads();
#pragma unroll
        for (int kh = 0; kh < 5; ++kh)
#pragma unroll
            for (int kw = 0; kw < 5; ++kw) {
                float xv = sx[(ty + kh)*20 + tx + kw];
#pragma unroll
                for (int e = 0; e < TE; ++e)
                    acc[e] = fmaf(xv, sw[e*25 + kh*5 + kw], acc[e]);
            }
        __syncthreads();
    }

    const int h = h0 + ty, wq = w0 + tx;
#pragma unroll
    for (int e = 0; e < TE; ++e) {
        float v = acc[e];
        if (do_relu) v = v > 0.f ? v : 0.f;
        size_t oidx = ((size_t)(b*Cout + e0 + e))*HW_ + h*WW + wq;
        if (addin) v += addin[oidx];
        out[oidx] = v;
    }
}

// Depthwise 5x5 surround-modulation conv, ZERO padding.
__global__ __launch_bounds__(256) void smconv_kernel(
    const float* __restrict__ in, const float* __restrict__ sm,
    float* __restrict__ out)
{
    __shared__ float sx[20*20];
    __shared__ float sw[25];
    const int tx = threadIdx.x, ty = threadIdx.y;
    const int tid = ty*16 + tx;
    const int tile = blockIdx.x;
    const int e = blockIdx.y;
    const int b = blockIdx.z;
    const int h0 = (tile >> 2) * 16, w0 = (tile & 3) * 16;
    const float* inc = in + ((size_t)(b*EXC_ + e))*HW_;
    for (int i = tid; i < 400; i += 256) {
        int lh = i / 20, lw = i - lh*20;
        int gh = h0 - 2 + lh, gw = w0 - 2 + lw;
        float v = 0.f;
        if (gh >= 0 && gh < HH && gw >= 0 && gw < WW) v = inc[gh*WW + gw];
        sx[i] = v;
    }
    if (tid < 25) sw[tid] = sm[tid];
    __syncthreads();
    float acc = 0.f;
#pragma unroll
    for (int kh = 0; kh < 5; ++kh)
#pragma unroll
        for (int kw = 0; kw < 5; ++kw)
            acc = fmaf(sx[(ty + kh)*20 + tx + kw], sw[kh*5 + kw], acc);
    out[((size_t)(b*EXC_ + e))*HW_ + (h0 + ty)*WW + (w0 + tx)] = acc;
}

// Per-pixel channel argmax (first-occurrence on strict >, matching np.argmax).
__global__ void wta_kernel(const float* __restrict__ in, int* __restrict__ win,
                           float* __restrict__ val, int C, int use_abs)
{
    int p = blockIdx.x*256 + threadIdx.x;   // 0..NPOS-1
    int b = p >> 12, hw = p & 4095;
    const float* base = in + ((size_t)b*C)*HW_ + hw;
    float bestv = base[0];
    float bestk = use_abs ? fabsf(bestv) : bestv;
    int besti = 0;
    for (int c = 1; c < C; ++c) {
        float v = base[(size_t)c*HW_];
        float key = use_abs ? fabsf(v) : v;
        if (key > bestk) { bestk = key; bestv = v; besti = c; }
    }
    win[p] = besti;
    val[p] = bestv;
}

// yx_ee[e,c] = sum_p [win_e==e] val_e * x[b,c,p];  yu_e[e] = sum val_e
__global__ __launch_bounds__(256) void scatter_ee_kernel(
    const float* __restrict__ x, const int* __restrict__ win_e,
    const float* __restrict__ val_e, float* __restrict__ yx_ee,
    float* __restrict__ yu_e)
{
    __shared__ float s_yx[EXC_*CIN_];   // 9792 floats
    __shared__ float s_yu[EXC_];
    for (int i = threadIdx.x; i < EXC_*CIN_; i += 256) s_yx[i] = 0.f;
    if (threadIdx.x < EXC_) s_yu[threadIdx.x] = 0.f;
    __syncthreads();
    int p0 = blockIdx.x * 512;          // 256 blocks x 512 positions
    for (int it = 0; it < 2; ++it) {
        int p = p0 + it*256 + threadIdx.x;
        int b = p >> 12, hw = p & 4095;
        int wi = win_e[p]; float v = val_e[p];
        atomicAdd(&s_yu[wi], v);
        const float* xb = x + ((size_t)b*CIN_)*HW_ + hw;
        float* row = s_yx + wi*CIN_;
        for (int c = 0; c < CIN_; ++c)
            atomicAdd(&row[c], v * xb[(size_t)c*HW_]);
    }
    __syncthreads();
    for (int i = threadIdx.x; i < EXC_*CIN_; i += 256) atomicAdd(&yx_ee[i], s_yx[i]);
    if (threadIdx.x < EXC_) atomicAdd(&yu_e[threadIdx.x], s_yu[threadIdx.x]);
}

// yx_ei[i,e] += val_e*val_i at (win_i,win_e);  yu_i[i] += |val_i|
__global__ __launch_bounds__(256) void scatter_ei_kernel(
    const int* __restrict__ win_e, const float* __restrict__ val_e,
    const int* __restrict__ win_i, const float* __restrict__ val_i,
    float* __restrict__ yx_ei, float* __restrict__ yu_i)
{
    __shared__ float s[INH_*EXC_ + INH_];  // 2652 + 26
    for (int i = threadIdx.x; i < INH_*EXC_ + INH_; i += 256) s[i] = 0.f;
    __syncthreads();
    int p0 = blockIdx.x * 1024;            // 128 blocks x 1024 positions
    for (int it = 0; it < 4; ++it) {
        int p = p0 + it*256 + threadIdx.x;
        int we = win_e[p]; float ve = val_e[p];
        int wi = win_i[p]; float vi = val_i[p];
        atomicAdd(&s[wi*EXC_ + we], ve*vi);
        atomicAdd(&s[INH_*EXC_ + wi], fabsf(vi));
    }
    __syncthreads();
    for (int i = threadIdx.x; i < INH_*EXC_ + INH_; i += 256) {
        float v = s[i];
        if (v != 0.f) {
            if (i < INH_*EXC_) atomicAdd(&yx_ei[i], v);
            else               atomicAdd(&yu_i[i - INH_*EXC_], v);
        }
    }
}

// yx_ie[e,i] = sum_p [win_i==i] val_i * y[b,e,p]
__global__ __launch_bounds__(256) void scatter_ie_kernel(
    const float* __restrict__ y, const int* __restrict__ win_i,
    const float* __restrict__ val_i, float* __restrict__ yx_ie)
{
    __shared__ float s[EXC_*INH_];  // 2652
    for (int i = threadIdx.x; i < EXC_*INH_; i += 256) s[i] = 0.f;
    __syncthreads();
    int p0 = blockIdx.x * 512;      // 256 blocks x 512 positions
    for (int it = 0; it < 2; ++it) {
        int p = p0 + it*256 + threadIdx.x;
        int b = p >> 12, hw = p & 4095;
        int wi = win_i[p]; float v = val_i[p];
        if (v != 0.f) {
            const float* yb = y + ((size_t)b*EXC_)*HW_ + hw;
            for (int e = 0; e < EXC_; ++e)
                atomicAdd(&s[e*INH_ + wi], v * yb[(size_t)e*HW_]);
        }
    }
    __syncthreads();
    for (int i = threadIdx.x; i < EXC_*INH_; i += 256) atomicAdd(&yx_ie[i], s[i]);
}

// absmax of upd = yx - yu[e]*w  (nonneg float bits are int-monotonic)
__global__ void upd_absmax_kernel(const float* __restrict__ yx,
    const float* __restrict__ yu, const float* __restrict__ w,
    int E, int C, unsigned int* __restrict__ amax)
{
    __shared__ unsigned int sm_;
    if (threadIdx.x == 0) sm_ = 0u;
    __syncthreads();
    int n = E*C*25;
    float m = 0.f;
    for (int idx = blockIdx.x*256 + threadIdx.x; idx < n; idx += gridDim.x*256) {
        int ec = idx / 25;
        int e = ec / C;
        float v = yx[ec] - yu[e]*w[idx];
        m = fmaxf(m, fabsf(v));
    }
    atomicMax(&sm_, __float_as_uint(m));
    __syncthreads();
    if (threadIdx.x == 0) atomicMax(amax, sm_);
}

__global__ void upd_write_kernel(const float* __restrict__ yx,
    const float* __restrict__ yu, const float* __restrict__ w,
    int E, int C, const unsigned int* __restrict__ amax,
    float* __restrict__ out)
{
    int n = E*C*25;
    int idx = blockIdx.x*256 + threadIdx.x;
    if (idx >= n) return;
    int ec = idx / 25;
    int e = ec / C;
    float v = yx[ec] - yu[e]*w[idx];
    float mx = __uint_as_float(*amax);
    out[idx] = v / (mx + 1e-8f);
}

extern "C" void kernel_launch(void* const* d_in, const int* in_sizes, int n_in,
                              void* d_out, int out_size, void* d_ws, size_t ws_size,
                              hipStream_t stream)
{
    const float* x    = (const float*)d_in[0];
    const float* w_ee = (const float*)d_in[1];
    const float* w_ei = (const float*)d_in[2];
    const float* w_ie = (const float*)d_in[3];
    const float* smk  = (const float*)d_in[4];
    float* out = (float*)d_out;

    // workspace layout (floats)
    float* ws    = (float*)d_ws;
    float* y_e   = ws;                                   // 13,369,344 (reused as y_pre in place)
    float* y_i   = y_e + (size_t)B_*EXC_*HW_;            // 3,407,872
    int*   win_e = (int*)(y_i + (size_t)B_*INH_*HW_);    // 131072
    float* val_e = (float*)(win_e + NPOS);               // 131072
    int*   win_i = (int*)(val_e + NPOS);                 // 131072
    float* val_i = (float*)(win_i + NPOS);               // 131072
    float* yx_ee = val_i + NPOS;                         // 9792
    float* yx_ei = yx_ee + EXC_*CIN_;                    // 2652
    float* yx_ie = yx_ei + INH_*EXC_;                    // 2652
    float* yu_e  = yx_ie + EXC_*INH_;                    // 102
    float* yu_i  = yu_e + EXC_;                          // 26
    unsigned int* amax = (unsigned int*)(yu_i + INH_);   // 3

    hipMemsetAsync(yx_ee, 0,
        (size_t)(EXC_*CIN_ + INH_*EXC_ + EXC_*INH_ + EXC_ + INH_ + 3)*sizeof(float),
        stream);

    dim3 blk(16,16);
    // y_e = conv(x, w_ee), reflect pad
    conv5x5_kernel<CIN_,6><<<dim3(16,17,B_), blk, 0, stream>>>(x, w_ee, nullptr, y_e, EXC_, 0);
    // WTA over excitatory channels (plain max)
    wta_kernel<<<NPOS/256, 256, 0, stream>>>(y_e, win_e, val_e, EXC_, 0);
    // y_i = relu(conv(y_e, w_ei)), reflect pad
    conv5x5_kernel<EXC_,13><<<dim3(16,2,B_), blk, 0, stream>>>(y_e, w_ei, nullptr, y_i, INH_, 1);
    // WTA over inhibitory channels (abs max, signed value kept)
    wta_kernel<<<NPOS/256, 256, 0, stream>>>(y_i, win_i, val_i, INH_, 1);
    // y_pre = y_e + conv(y_i, w_ie), reflect pad  (in place over y_e)
    conv5x5_kernel<INH_,6><<<dim3(16,17,B_), blk, 0, stream>>>(y_i, w_ie, y_e, y_e, EXC_, 0);
    // y = depthwise sm conv (zero pad) -> d_out chunk 0
    smconv_kernel<<<dim3(16,EXC_,B_), blk, 0, stream>>>(y_e, smk, out);

    // Hebbian scatters
    scatter_ee_kernel<<<256, 256, 0, stream>>>(x, win_e, val_e, yx_ee, yu_e);
    scatter_ei_kernel<<<128, 256, 0, stream>>>(win_e, val_e, win_i, val_i, yx_ei, yu_i);
    scatter_ie_kernel<<<256, 256, 0, stream>>>(out, win_i, val_i, yx_ie);

    // upd normalization
    upd_absmax_kernel<<<240, 256, 0, stream>>>(yx_ee, yu_e, w_ee, EXC_, CIN_, amax+0);
    upd_absmax_kernel<<<240, 256, 0, stream>>>(yx_ei, yu_i, w_ei, INH_, EXC_, amax+1);
    upd_absmax_kernel<<<240, 256, 0, stream>>>(yx_ie, yu_e, w_ie, EXC_, INH_, amax+2);

    float* out_ee = out + (size_t)B_*EXC_*HW_;
    float* out_ei = out_ee + EXC_*CIN_*25;
    float* out_ie = out_ei + INH_*EXC_*25;
    upd_write_kernel<<<(EXC_*CIN_*25+255)/256, 256, 0, stream>>>(yx_ee, yu_e, w_ee, EXC_, CIN_, amax+0, out_ee);
    upd_write_kernel<<<(INH_*EXC_*25+255)/256, 256, 0, stream>>>(yx_ei, yu_i, w_ei, INH_, EXC_, amax+1, out_ei);
    upd_write_kernel<<<(EXC_*INH_*25+255)/256, 256, 0, stream>>>(yx_ie, yu_e, w_ie, EXC_, INH_, amax+2, out_ie);
}

// Round 2
// 1831.322 us; speedup vs baseline: 2.2133x; 2.2133x over previous
//
#include <hip/hip_runtime.h>

#define B_    32
#define CIN_  96
#define EXC_  102
#define INH_  26
#define HH    64
#define WW    64
#define HW_   4096
#define NPOS  (B_*HW_)   // 131072

__device__ __forceinline__ int refl(int i) {
    if (i < 0) i = -i;
    if (i > 63) i = 126 - i;
    return i;
}

// ---------------------------------------------------------------------------
// Direct 5x5 conv, reflect padding. 32x32 output tile per block, 256 threads,
// each thread computes TW=4 consecutive horizontal pixels x TE channels.
// Weights are wave-uniform -> compiler emits s_load (scalar) -> FMA-bound.
// addin may alias out (same-element read-before-write).
// ---------------------------------------------------------------------------
template<int CIN, int TE>
__global__ __launch_bounds__(256) void conv5x5_v2(
    const float* __restrict__ in, const float* __restrict__ wgt,
    const float* __restrict__ addin, float* __restrict__ out,
    int Cout, int do_relu)
{
    __shared__ __align__(16) float sx[36*36];   // one input channel tile
    __shared__ int ghs[36], gws[36];
    const int tid = threadIdx.x;
    const int tile = blockIdx.x;            // 0..3 (2x2 tiles of 32x32)
    const int e0 = blockIdx.y * TE;
    const int b  = blockIdx.z;
    const int h0 = (tile >> 1) * 32;
    const int w0 = (tile &  1) * 32;
    const int r  = tid >> 3;                // 0..31 output row in tile
    const int cg = (tid & 7) * 4;           // output col group (4 px)

    if (tid < 36)       ghs[tid]    = refl(h0 - 2 + tid);
    else if (tid < 72)  gws[tid-36] = refl(w0 - 2 + (tid - 36));

    float acc[TE][4];
#pragma unroll
    for (int e = 0; e < TE; ++e)
#pragma unroll
        for (int j = 0; j < 4; ++j) acc[e][j] = 0.f;

    __syncthreads();

    for (int c = 0; c < CIN; ++c) {
        const float* inc = in + ((size_t)(b*CIN + c)) * HW_;
#pragma unroll
        for (int it = 0; it < 6; ++it) {
            int i = tid + it*256;
            if (i < 1296) {
                int lh = i / 36, lw = i - lh*36;
                sx[i] = inc[ghs[lh]*WW + gws[lw]];
            }
        }
        const float* wc = wgt + (size_t)c*25;   // + e*CIN*25 below (uniform)
        __syncthreads();
#pragma unroll
        for (int kh = 0; kh < 5; ++kh) {
            const float4* rowp = (const float4*)(sx + (r + kh)*36 + cg);
            float4 v0 = rowp[0], v1 = rowp[1];
            float xv[8] = {v0.x, v0.y, v0.z, v0.w, v1.x, v1.y, v1.z, v1.w};
#pragma unroll
            for (int kw = 0; kw < 5; ++kw) {
#pragma unroll
                for (int e = 0; e < TE; ++e) {
                    int ee = e0 + e; if (ee >= Cout) ee = Cout - 1;  // clamp (uniform)
                    float wv = wc[(size_t)ee*CIN*25 + kh*5 + kw];
#pragma unroll
                    for (int j = 0; j < 4; ++j)
                        acc[e][j] = fmaf(xv[kw + j], wv, acc[e][j]);
                }
            }
        }
        __syncthreads();
    }

    const int h = h0 + r, wq = w0 + cg;
#pragma unroll
    for (int e = 0; e < TE; ++e) {
        if (e0 + e < Cout) {
            size_t oidx = ((size_t)(b*Cout + e0 + e))*HW_ + h*WW + wq;
            float4 v = make_float4(acc[e][0], acc[e][1], acc[e][2], acc[e][3]);
            if (do_relu) {
                v.x = fmaxf(v.x, 0.f); v.y = fmaxf(v.y, 0.f);
                v.z = fmaxf(v.z, 0.f); v.w = fmaxf(v.w, 0.f);
            }
            if (addin) {
                const float4 a = *(const float4*)(addin + oidx);
                v.x += a.x; v.y += a.y; v.z += a.z; v.w += a.w;
            }
            *(float4*)(out + oidx) = v;
        }
    }
}

// Depthwise 5x5 surround-modulation conv, ZERO padding. 32x32 tile, TW=4.
__global__ __launch_bounds__(256) void smconv_v2(
    const float* __restrict__ in, const float* __restrict__ sm,
    float* __restrict__ out)
{
    __shared__ __align__(16) float sx[36*36];
    const int tid = threadIdx.x;
    const int tile = blockIdx.x;
    const int e = blockIdx.y;
    const int b = blockIdx.z;
    const int h0 = (tile >> 1) * 32, w0 = (tile & 1) * 32;
    const int r  = tid >> 3;
    const int cg = (tid & 7) * 4;
    const float* inc = in + ((size_t)(b*EXC_ + e))*HW_;
#pragma unroll
    for (int it = 0; it < 6; ++it) {
        int i = tid + it*256;
        if (i < 1296) {
            int lh = i / 36, lw = i - lh*36;
            int gh = h0 - 2 + lh, gw = w0 - 2 + lw;
            float v = 0.f;
            if (gh >= 0 && gh < HH && gw >= 0 && gw < WW) v = inc[gh*WW + gw];
            sx[i] = v;
        }
    }
    __syncthreads();
    float a0 = 0.f, a1 = 0.f, a2 = 0.f, a3 = 0.f;
#pragma unroll
    for (int kh = 0; kh < 5; ++kh) {
        const float4* rowp = (const float4*)(sx + (r + kh)*36 + cg);
        float4 v0 = rowp[0], v1 = rowp[1];
        float xv[8] = {v0.x, v0.y, v0.z, v0.w, v1.x, v1.y, v1.z, v1.w};
#pragma unroll
        for (int kw = 0; kw < 5; ++kw) {
            float wv = sm[kh*5 + kw];
            a0 = fmaf(xv[kw+0], wv, a0);
            a1 = fmaf(xv[kw+1], wv, a1);
            a2 = fmaf(xv[kw+2], wv, a2);
            a3 = fmaf(xv[kw+3], wv, a3);
        }
    }
    size_t oidx = ((size_t)(b*EXC_ + e))*HW_ + (h0 + r)*WW + w0 + cg;
    *(float4*)(out + oidx) = make_float4(a0, a1, a2, a3);
}

// Per-pixel channel argmax (first-occurrence on strict >, matching np.argmax).
__global__ void wta_kernel(const float* __restrict__ in, int* __restrict__ win,
                           float* __restrict__ val, int C, int use_abs)
{
    int p = blockIdx.x*256 + threadIdx.x;   // 0..NPOS-1
    int b = p >> 12, hw = p & 4095;
    const float* base = in + ((size_t)b*C)*HW_ + hw;
    float bestv = base[0];
    float bestk = use_abs ? fabsf(bestv) : bestv;
    int besti = 0;
    for (int c = 1; c < C; ++c) {
        float v = base[(size_t)c*HW_];
        float key = use_abs ? fabsf(v) : v;
        if (key > bestk) { bestk = key; bestv = v; besti = c; }
    }
    win[p] = besti;
    val[p] = bestv;
}

// yx_ee[e,c] = sum_p [win_e==e] val_e * x[b,c,p];  yu_e[e] = sum val_e
__global__ __launch_bounds__(256) void scatter_ee_kernel(
    const float* __restrict__ x, const int* __restrict__ win_e,
    const float* __restrict__ val_e, float* __restrict__ yx_ee,
    float* __restrict__ yu_e)
{
    __shared__ float s_yx[EXC_*CIN_];   // 9792 floats
    __shared__ float s_yu[EXC_];
    for (int i = threadIdx.x; i < EXC_*CIN_; i += 256) s_yx[i] = 0.f;
    if (threadIdx.x < EXC_) s_yu[threadIdx.x] = 0.f;
    __syncthreads();
    int p0 = blockIdx.x * 512;          // 256 blocks x 512 positions
    for (int it = 0; it < 2; ++it) {
        int p = p0 + it*256 + threadIdx.x;
        int b = p >> 12, hw = p & 4095;
        int wi = win_e[p]; float v = val_e[p];
        atomicAdd(&s_yu[wi], v);
        const float* xb = x + ((size_t)b*CIN_)*HW_ + hw;
        float* row = s_yx + wi*CIN_;
        for (int c = 0; c < CIN_; ++c)
            atomicAdd(&row[c], v * xb[(size_t)c*HW_]);
    }
    __syncthreads();
    for (int i = threadIdx.x; i < EXC_*CIN_; i += 256) atomicAdd(&yx_ee[i], s_yx[i]);
    if (threadIdx.x < EXC_) atomicAdd(&yu_e[threadIdx.x], s_yu[threadIdx.x]);
}

// yx_ei[i,e] += val_e*val_i at (win_i,win_e);  yu_i[i] += |val_i|
__global__ __launch_bounds__(256) void scatter_ei_kernel(
    const int* __restrict__ win_e, const float* __restrict__ val_e,
    const int* __restrict__ win_i, const float* __restrict__ val_i,
    float* __restrict__ yx_ei, float* __restrict__ yu_i)
{
    __shared__ float s[INH_*EXC_ + INH_];  // 2652 + 26
    for (int i = threadIdx.x; i < INH_*EXC_ + INH_; i += 256) s[i] = 0.f;
    __syncthreads();
    int p0 = blockIdx.x * 1024;            // 128 blocks x 1024 positions
    for (int it = 0; it < 4; ++it) {
        int p = p0 + it*256 + threadIdx.x;
        int we = win_e[p]; float ve = val_e[p];
        int wi = win_i[p]; float vi = val_i[p];
        atomicAdd(&s[wi*EXC_ + we], ve*vi);
        atomicAdd(&s[INH_*EXC_ + wi], fabsf(vi));
    }
    __syncthreads();
    for (int i = threadIdx.x; i < INH_*EXC_ + INH_; i += 256) {
        float v = s[i];
        if (v != 0.f) {
            if (i < INH_*EXC_) atomicAdd(&yx_ei[i], v);
            else               atomicAdd(&yu_i[i - INH_*EXC_], v);
        }
    }
}

// yx_ie[e,i] = sum_p [win_i==i] val_i * y[b,e,p]
__global__ __launch_bounds__(256) void scatter_ie_kernel(
    const float* __restrict__ y, const int* __restrict__ win_i,
    const float* __restrict__ val_i, float* __restrict__ yx_ie)
{
    __shared__ float s[EXC_*INH_];  // 2652
    for (int i = threadIdx.x; i < EXC_*INH_; i += 256) s[i] = 0.f;
    __syncthreads();
    int p0 = blockIdx.x * 512;      // 256 blocks x 512 positions
    for (int it = 0; it < 2; ++it) {
        int p = p0 + it*256 + threadIdx.x;
        int b = p >> 12, hw = p & 4095;
        int wi = win_i[p]; float v = val_i[p];
        if (v != 0.f) {
            const float* yb = y + ((size_t)b*EXC_)*HW_ + hw;
            for (int e = 0; e < EXC_; ++e)
                atomicAdd(&s[e*INH_ + wi], v * yb[(size_t)e*HW_]);
        }
    }
    __syncthreads();
    for (int i = threadIdx.x; i < EXC_*INH_; i += 256) atomicAdd(&yx_ie[i], s[i]);
}

// absmax of upd = yx - yu[e]*w  (nonneg float bits are int-monotonic)
__global__ void upd_absmax_kernel(const float* __restrict__ yx,
    const float* __restrict__ yu, const float* __restrict__ w,
    int E, int C, unsigned int* __restrict__ amax)
{
    __shared__ unsigned int sm_;
    if (threadIdx.x == 0) sm_ = 0u;
    __syncthreads();
    int n = E*C*25;
    float m = 0.f;
    for (int idx = blockIdx.x*256 + threadIdx.x; idx < n; idx += gridDim.x*256) {
        int ec = idx / 25;
        int e = ec / C;
        float v = yx[ec] - yu[e]*w[idx];
        m = fmaxf(m, fabsf(v));
    }
    atomicMax(&sm_, __float_as_uint(m));
    __syncthreads();
    if (threadIdx.x == 0) atomicMax(amax, sm_);
}

__global__ void upd_write_kernel(const float* __restrict__ yx,
    const float* __restrict__ yu, const float* __restrict__ w,
    int E, int C, const unsigned int* __restrict__ amax,
    float* __restrict__ out)
{
    int n = E*C*25;
    int idx = blockIdx.x*256 + threadIdx.x;
    if (idx >= n) return;
    int ec = idx / 25;
    int e = ec / C;
    float v = yx[ec] - yu[e]*w[idx];
    float mx = __uint_as_float(*amax);
    out[idx] = v / (mx + 1e-8f);
}

extern "C" void kernel_launch(void* const* d_in, const int* in_sizes, int n_in,
                              void* d_out, int out_size, void* d_ws, size_t ws_size,
                              hipStream_t stream)
{
    const float* x    = (const float*)d_in[0];
    const float* w_ee = (const float*)d_in[1];
    const float* w_ei = (const float*)d_in[2];
    const float* w_ie = (const float*)d_in[3];
    const float* smk  = (const float*)d_in[4];
    float* out = (float*)d_out;

    // workspace layout (floats)
    float* ws    = (float*)d_ws;
    float* y_e   = ws;                                   // 13,369,344 (reused as y_pre in place)
    float* y_i   = y_e + (size_t)B_*EXC_*HW_;            // 3,407,872
    int*   win_e = (int*)(y_i + (size_t)B_*INH_*HW_);    // 131072
    float* val_e = (float*)(win_e + NPOS);               // 131072
    int*   win_i = (int*)(val_e + NPOS);                 // 131072
    float* val_i = (float*)(win_i + NPOS);               // 131072
    float* yx_ee = val_i + NPOS;                         // 9792
    float* yx_ei = yx_ee + EXC_*CIN_;                    // 2652
    float* yx_ie = yx_ei + INH_*EXC_;                    // 2652
    float* yu_e  = yx_ie + EXC_*INH_;                    // 102
    float* yu_i  = yu_e + EXC_;                          // 26
    unsigned int* amax = (unsigned int*)(yu_i + INH_);   // 3

    hipMemsetAsync(yx_ee, 0,
        (size_t)(EXC_*CIN_ + INH_*EXC_ + EXC_*INH_ + EXC_ + INH_ + 3)*sizeof(float),
        stream);

    // y_e = conv(x, w_ee), reflect pad                       [TE=6, 17 groups]
    conv5x5_v2<CIN_,6><<<dim3(4,17,B_), 256, 0, stream>>>(x, w_ee, nullptr, y_e, EXC_, 0);
    // WTA over excitatory channels (plain max)
    wta_kernel<<<NPOS/256, 256, 0, stream>>>(y_e, win_e, val_e, EXC_, 0);
    // y_i = relu(conv(y_e, w_ei)), reflect pad               [TE=7, 4 groups, clamp]
    conv5x5_v2<EXC_,7><<<dim3(4,4,B_), 256, 0, stream>>>(y_e, w_ei, nullptr, y_i, INH_, 1);
    // WTA over inhibitory channels (abs max, signed value kept)
    wta_kernel<<<NPOS/256, 256, 0, stream>>>(y_i, win_i, val_i, INH_, 1);
    // y_pre = y_e + conv(y_i, w_ie), reflect pad (in place over y_e)
    conv5x5_v2<INH_,6><<<dim3(4,17,B_), 256, 0, stream>>>(y_i, w_ie, y_e, y_e, EXC_, 0);
    // y = depthwise sm conv (zero pad) -> d_out chunk 0
    smconv_v2<<<dim3(4,EXC_,B_), 256, 0, stream>>>(y_e, smk, out);

    // Hebbian scatters
    scatter_ee_kernel<<<256, 256, 0, stream>>>(x, win_e, val_e, yx_ee, yu_e);
    scatter_ei_kernel<<<128, 256, 0, stream>>>(win_e, val_e, win_i, val_i, yx_ei, yu_i);
    scatter_ie_kernel<<<256, 256, 0, stream>>>(out, win_i, val_i, yx_ie);

    // upd normalization
    upd_absmax_kernel<<<240, 256, 0, stream>>>(yx_ee, yu_e, w_ee, EXC_, CIN_, amax+0);
    upd_absmax_kernel<<<240, 256, 0, stream>>>(yx_ei, yu_i, w_ei, INH_, EXC_, amax+1);
    upd_absmax_kernel<<<240, 256, 0, stream>>>(yx_ie, yu_e, w_ie, EXC_, INH_, amax+2);

    float* out_ee = out + (size_t)B_*EXC_*HW_;
    float* out_ei = out_ee + EXC_*CIN_*25;
    float* out_ie = out_ei + INH_*EXC_*25;
    upd_write_kernel<<<(EXC_*CIN_*25+255)/256, 256, 0, stream>>>(yx_ee, yu_e, w_ee, EXC_, CIN_, amax+0, out_ee);
    upd_write_kernel<<<(INH_*EXC_*25+255)/256, 256, 0, stream>>>(yx_ei, yu_i, w_ei, INH_, EXC_, amax+1, out_ei);
    upd_write_kernel<<<(EXC_*INH_*25+255)/256, 256, 0, stream>>>(yx_ie, yu_e, w_ie, EXC_, INH_, amax+2, out_ie);
}